// Round 11
// baseline (230.487 us; speedup 1.0000x reference)
//
#include <hip/hip_runtime.h>
#include <math.h>

#define D     172
#define D4    43            // float4s per row
#define G3    516           // 3*D rows per weight matrix
#define RPB   8             // batch rows per GRU block
#define TPB   256
#define NGRU  512           // B/RPB (B=4096)
#define WT_HALF (43 * 516)          // float4s per transposed matrix = 22188
#define WT_F4   (2 * WT_HALF)       // 44376

typedef float vfloat4 __attribute__((ext_vector_type(4)));

// ---------------------------------------------------------------------------
// Prologue: transpose weights into ws as Wt[m][k4][row] (float4 over k) so
// GRU weight loads are coalesced across lanes (lane d -> consecutive f4).
// ---------------------------------------------------------------------------
__global__ __launch_bounds__(256) void prep_kernel(const float* __restrict__ w_ih,
                                                   const float* __restrict__ w_hh,
                                                   float4* __restrict__ wt) {
    int idx = blockIdx.x * 256 + threadIdx.x;
    if (idx < WT_F4) {
        int m   = idx / WT_HALF;
        int rem = idx - m * WT_HALF;
        int k4  = rem / G3;
        int row = rem - k4 * G3;
        const float* src = m ? w_hh : w_ih;
        wt[idx] = *(const float4*)(src + (long)row * D + 4 * k4);
    }
}

// ---------------------------------------------------------------------------
// GRU body (unchanged from R6-fixed): 8 rows per block, results -> scratch.
// Dup flag via shared-memory OR (benign race). __ballot is per-wave (64) on
// CDNA — never use it for a 256-thread block reduction (R5's bug).
// ---------------------------------------------------------------------------
__device__ __forceinline__ void gru_block(
    int gblk,
    const int*   __restrict__ ids,  const float* __restrict__ msg,
    const float* __restrict__ ts,   const float* __restrict__ mem,
    const float* __restrict__ b_ih, const float* __restrict__ b_hh,
    const float4* __restrict__ wt,
    float* __restrict__ gout, int* __restrict__ g_id,
    float* __restrict__ g_ts, int* __restrict__ g_dup,
    int B) {

    __shared__ float4 sxh[2][RPB][D4];   // [0]=x (messages), [1]=h (gathered memory)
    __shared__ int    s_id[RPB];
    __shared__ int    s_dup[RPB];

    const int tid  = threadIdx.x;
    const int base = gblk * RPB;

    if (tid < RPB) {
        int id = ids[base + tid];
        s_id[tid]  = id;
        s_dup[tid] = 0;
        g_id[base + tid] = id;
        g_ts[base + tid] = ts[base + tid];
    }
    __syncthreads();

    for (int it = tid; it < 2 * RPB * D4; it += TPB) {
        int which = it / (RPB * D4);
        int rem   = it - which * (RPB * D4);
        int r     = rem / D4;
        int k4    = rem - r * D4;
        const float* src = which ? (mem + (long)s_id[r] * D)
                                 : (msg + (long)(base + r) * D);
        ((float4*)sxh)[it] = *(const float4*)(src + 4 * k4);
    }
    // duplicate scan: row r loses if any later batch index has the same id
    for (int r = 0; r < RPB; ++r) {
        int my = s_id[r];
        for (int j = base + r + 1 + tid; j < B; j += TPB) {
            if (ids[j] == my) { s_dup[r] = 1; break; }
        }
    }
    __syncthreads();
    if (tid < RPB) g_dup[base + tid] = s_dup[tid];

    if (tid < D) {
        float acc[6][RPB];
        #pragma unroll
        for (int g = 0; g < 6; ++g)
            #pragma unroll
            for (int r = 0; r < RPB; ++r) acc[g][r] = 0.0f;

        const float4* wtB = wt + WT_HALF;
        for (int k4 = 0; k4 < D4; ++k4) {
            const int o = k4 * G3 + tid;
            float4 a0 = wt [o];
            float4 a1 = wt [o + D];
            float4 a2 = wt [o + 2 * D];
            float4 c0 = wtB[o];
            float4 c1 = wtB[o + D];
            float4 c2 = wtB[o + 2 * D];
            #pragma unroll
            for (int r = 0; r < RPB; ++r) {
                float4 xv = sxh[0][r][k4];
                float4 hv = sxh[1][r][k4];
                acc[0][r] += a0.x * xv.x + a0.y * xv.y + a0.z * xv.z + a0.w * xv.w;
                acc[1][r] += a1.x * xv.x + a1.y * xv.y + a1.z * xv.z + a1.w * xv.w;
                acc[2][r] += a2.x * xv.x + a2.y * xv.y + a2.z * xv.z + a2.w * xv.w;
                acc[3][r] += c0.x * hv.x + c0.y * hv.y + c0.z * hv.z + c0.w * hv.w;
                acc[4][r] += c1.x * hv.x + c1.y * hv.y + c1.z * hv.z + c1.w * hv.w;
                acc[5][r] += c2.x * hv.x + c2.y * hv.y + c2.z * hv.z + c2.w * hv.w;
            }
        }

        float bir = b_ih[tid], biz = b_ih[D + tid], bin_ = b_ih[2 * D + tid];
        float bhr = b_hh[tid], bhz = b_hh[D + tid], bhn  = b_hh[2 * D + tid];
        #pragma unroll
        for (int r = 0; r < RPB; ++r) {
            float i_r = acc[0][r] + bir;
            float i_z = acc[1][r] + biz;
            float i_n = acc[2][r] + bin_;
            float h_r = acc[3][r] + bhr;
            float h_z = acc[4][r] + bhz;
            float h_n = acc[5][r] + bhn;
            float rg = 1.0f / (1.0f + expf(-(i_r + h_r)));
            float zg = 1.0f / (1.0f + expf(-(i_z + h_z)));
            float ng = tanhf(i_n + rg * h_n);
            float hv = ((const float*)sxh[1][r])[tid];
            gout[(long)(base + r) * D + tid] = (1.0f - zg) * ng + zg * hv;
        }
    }
}

// ---------------------------------------------------------------------------
// Fused kernel: blocks [0,NGRU) = GRU into scratch (writes only d_ws, no
// conflict with copy); blocks [NGRU, NGRU+nblk) = MONOLITHIC one-float4-per-
// thread copy (R10's proven ~fast form: no loop, fire-and-forget).
// ---------------------------------------------------------------------------
__global__ __launch_bounds__(TPB) void fused_kernel(
    const int*   __restrict__ ids,  const float* __restrict__ msg,
    const float* __restrict__ ts,   const float* __restrict__ mem,
    const float* __restrict__ lu,
    const float* __restrict__ b_ih, const float* __restrict__ b_hh,
    const float4* __restrict__ wt,
    float* __restrict__ gout, int* __restrict__ g_id,
    float* __restrict__ g_ts, int* __restrict__ g_dup,
    float* __restrict__ out_mem,    float* __restrict__ out_lu,
    int B, unsigned memf4, unsigned totalf4) {

    if (blockIdx.x < NGRU) {
        gru_block(blockIdx.x, ids, msg, ts, mem, b_ih, b_hh, wt,
                  gout, g_id, g_ts, g_dup, B);
        return;
    }
    unsigned gid = (blockIdx.x - NGRU) * TPB + threadIdx.x;
    const vfloat4* src4 = (const vfloat4*)mem;
    vfloat4* dst4 = (vfloat4*)out_mem;
    if (gid < memf4) {
        dst4[gid] = src4[gid];
    } else if (gid < totalf4) {
        ((vfloat4*)out_lu)[gid - memf4] = ((const vfloat4*)lu)[gid - memf4];
    }
}

// ---------------------------------------------------------------------------
// Epilogue: scatter winner GRU rows + timestamps into the output (2.8 MB).
// ---------------------------------------------------------------------------
__global__ __launch_bounds__(TPB) void scatter_kernel(
    const float* __restrict__ gout, const int* __restrict__ g_id,
    const float* __restrict__ g_ts, const int* __restrict__ g_dup,
    float* __restrict__ out_mem, float* __restrict__ out_lu, int B) {
    int idx = blockIdx.x * TPB + threadIdx.x;
    int total = B * D;
    if (idx < total) {
        int r = idx / D;
        int d = idx - r * D;
        if (!g_dup[r]) out_mem[(long)g_id[r] * D + d] = gout[idx];
    } else if (idx < total + B) {
        int r = idx - total;
        if (!g_dup[r]) out_lu[g_id[r]] = g_ts[r];
    }
}

// ---------------- fallback (serial R10 path, used only if ws too small) ----
__global__ __launch_bounds__(TPB) void copy1_kernel(const vfloat4* __restrict__ src,
                                                    vfloat4* __restrict__ dst,
                                                    const vfloat4* __restrict__ lu4,
                                                    vfloat4* __restrict__ outlu4,
                                                    unsigned memf4, unsigned totalf4) {
    unsigned gid = blockIdx.x * TPB + threadIdx.x;
    if (gid < memf4) {
        dst[gid] = src[gid];
    } else if (gid < totalf4) {
        outlu4[gid - memf4] = lu4[gid - memf4];
    }
}

__global__ __launch_bounds__(TPB) void gru_direct_kernel(
    const int*   __restrict__ ids,  const float* __restrict__ msg,
    const float* __restrict__ ts,   const float* __restrict__ mem,
    const float* __restrict__ w_ih, const float* __restrict__ w_hh,
    const float* __restrict__ b_ih, const float* __restrict__ b_hh,
    float* __restrict__ out_mem,    float* __restrict__ out_lu, int B) {
    int r = blockIdx.x;
    int tid = threadIdx.x;
    __shared__ float sx[D], sh[D];
    __shared__ int s_id, s_dup;
    if (tid == 0) { s_id = ids[r]; s_dup = 0; }
    __syncthreads();
    if (tid < D) { sx[tid] = msg[(long)r * D + tid]; sh[tid] = mem[(long)s_id * D + tid]; }
    for (int j = r + 1 + tid; j < B; j += TPB) if (ids[j] == s_id) { s_dup = 1; break; }
    __syncthreads();
    if (s_dup) return;
    if (tid < D) {
        float a[6] = {0,0,0,0,0,0};
        for (int k = 0; k < D; ++k) {
            float xv = sx[k], hv = sh[k];
            a[0] += w_ih[(long)(0*D+tid)*D+k] * xv;
            a[1] += w_ih[(long)(1*D+tid)*D+k] * xv;
            a[2] += w_ih[(long)(2*D+tid)*D+k] * xv;
            a[3] += w_hh[(long)(0*D+tid)*D+k] * hv;
            a[4] += w_hh[(long)(1*D+tid)*D+k] * hv;
            a[5] += w_hh[(long)(2*D+tid)*D+k] * hv;
        }
        float rg = 1.0f / (1.0f + expf(-(a[0] + b_ih[tid] + a[3] + b_hh[tid])));
        float zg = 1.0f / (1.0f + expf(-(a[1] + b_ih[D+tid] + a[4] + b_hh[D+tid])));
        float ng = tanhf(a[2] + b_ih[2*D+tid] + rg * (a[5] + b_hh[2*D+tid]));
        out_mem[(long)s_id * D + tid] = (1.0f - zg) * ng + zg * sh[tid];
    }
    if (tid == 0) out_lu[s_id] = ts[r];
}

extern "C" void kernel_launch(void* const* d_in, const int* in_sizes, int n_in,
                              void* d_out, int out_size, void* d_ws, size_t ws_size,
                              hipStream_t stream) {
    const int*   node_ids    = (const int*)d_in[0];
    const float* messages    = (const float*)d_in[1];
    const float* timestamps  = (const float*)d_in[2];
    const float* memory      = (const float*)d_in[3];
    const float* last_update = (const float*)d_in[4];
    const float* w_ih        = (const float*)d_in[5];
    const float* w_hh        = (const float*)d_in[6];
    const float* b_ih        = (const float*)d_in[7];
    const float* b_hh        = (const float*)d_in[8];
    float* out = (float*)d_out;

    const int B = in_sizes[0];          // 4096
    const int N = in_sizes[4];          // 500000
    const long memf = (long)N * D;      // 86,000,000 floats

    const unsigned memf4   = (unsigned)(memf / 4);       // 21,500,000
    const unsigned totalf4 = memf4 + (unsigned)(N / 4);  // +125,000
    const unsigned nblk    = (totalf4 + TPB - 1) / TPB;  // 84,473

    // ws layout: wt | gout | g_id | g_ts | g_dup
    size_t off_wt   = 0;
    size_t off_gout = off_wt + (size_t)WT_F4 * 16;
    size_t off_id   = off_gout + (size_t)B * D * 4;
    size_t off_ts   = off_id + (size_t)B * 4;
    size_t off_dup  = off_ts + (size_t)B * 4;
    size_t ws_need  = off_dup + (size_t)B * 4;

    if (ws_size >= ws_need) {
        float4* wt    = (float4*)((char*)d_ws + off_wt);
        float*  gout  = (float*)((char*)d_ws + off_gout);
        int*    g_id  = (int*)((char*)d_ws + off_id);
        float*  g_ts  = (float*)((char*)d_ws + off_ts);
        int*    g_dup = (int*)((char*)d_ws + off_dup);

        prep_kernel<<<(WT_F4 + 255) / 256, 256, 0, stream>>>(w_ih, w_hh, wt);
        fused_kernel<<<NGRU + nblk, TPB, 0, stream>>>(
            node_ids, messages, timestamps, memory, last_update,
            b_ih, b_hh, (const float4*)wt,
            gout, g_id, g_ts, g_dup, out, out + memf, B, memf4, totalf4);
        scatter_kernel<<<(B * D + B + TPB - 1) / TPB, TPB, 0, stream>>>(
            gout, g_id, g_ts, g_dup, out, out + memf, B);
    } else {
        copy1_kernel<<<nblk, TPB, 0, stream>>>((const vfloat4*)memory,
                                               (vfloat4*)out,
                                               (const vfloat4*)last_update,
                                               (vfloat4*)(out + memf),
                                               memf4, totalf4);
        gru_direct_kernel<<<B, TPB, 0, stream>>>(node_ids, messages, timestamps, memory,
                                                 w_ih, w_hh, b_ih, b_hh,
                                                 out, out + memf, B);
    }
}

// Round 12
// 214.152 us; speedup vs baseline: 1.0763x; 1.0763x over previous
//
#include <hip/hip_runtime.h>
#include <math.h>

#define D     172
#define D4    43            // float4s per row
#define G3    516           // 3*D rows per weight matrix
#define RPB   8             // batch rows per GRU block
#define TPB   256
#define WT_HALF (43 * 516)          // float4s per transposed matrix = 22188
#define WT_F4   (2 * WT_HALF)       // 44376

typedef float vfloat4 __attribute__((ext_vector_type(4)));

// ---------------------------------------------------------------------------
// Prologue: transpose weights into ws as Wt[m][k4][row] (float4 over k) so
// GRU weight loads are coalesced across lanes (lane d -> consecutive f4).
// ---------------------------------------------------------------------------
__global__ __launch_bounds__(256) void prep_kernel(const float* __restrict__ w_ih,
                                                   const float* __restrict__ w_hh,
                                                   float4* __restrict__ wt) {
    int idx = blockIdx.x * 256 + threadIdx.x;
    if (idx < WT_F4) {
        int m   = idx / WT_HALF;
        int rem = idx - m * WT_HALF;
        int k4  = rem / G3;
        int row = rem - k4 * G3;
        const float* src = m ? w_hh : w_ih;
        wt[idx] = *(const float4*)(src + (long)row * D + 4 * k4);
    }
}

// ---------------------------------------------------------------------------
// Copy kernel — monolithic (no loop), FOUR adjacent float4s per thread with
// all loads issued before any store. 64 B/lane in flight -> progressive
// vmcnt(3..0) instead of one access/lane (R10, ~4.4 TB/s nominal). Lean:
// ~24 VGPR, no LDS, so copy occupancy stays high (R11 showed fusing with the
// GRU forces 116 VGPR/11KB LDS on copy blocks -> 20% occupancy -> 2.3 TB/s;
// never fuse fat and lean block roles).
// Quad counts divide exactly: memf4 = 21.5M = 4*5.375M, luf4 = 125K = 4*31250.
// ---------------------------------------------------------------------------
__global__ __launch_bounds__(TPB) void copy4_kernel(const vfloat4* __restrict__ src,
                                                    vfloat4* __restrict__ dst,
                                                    const vfloat4* __restrict__ lu4,
                                                    vfloat4* __restrict__ outlu4,
                                                    unsigned quads_mem, unsigned quads_total) {
    unsigned gid = blockIdx.x * TPB + threadIdx.x;
    if (gid < quads_mem) {
        unsigned b = 4u * gid;
        vfloat4 a0 = src[b];
        vfloat4 a1 = src[b + 1u];
        vfloat4 a2 = src[b + 2u];
        vfloat4 a3 = src[b + 3u];
        dst[b]      = a0;
        dst[b + 1u] = a1;
        dst[b + 2u] = a2;
        dst[b + 3u] = a3;
    } else if (gid < quads_total) {
        unsigned b = 4u * (gid - quads_mem);
        vfloat4 a0 = lu4[b];
        vfloat4 a1 = lu4[b + 1u];
        vfloat4 a2 = lu4[b + 2u];
        vfloat4 a3 = lu4[b + 3u];
        outlu4[b]      = a0;
        outlu4[b + 1u] = a1;
        outlu4[b + 2u] = a2;
        outlu4[b + 3u] = a3;
    }
}

// ---------------------------------------------------------------------------
// GRU kernel (runs AFTER the bulk copy): computes 8 batch rows per block and
// scatters winner rows + timestamps directly into the output. Dup
// suppression: shared-memory flag any thread may set (benign OR-race);
// NOTE: __ballot is per-wave (64 lanes) on CDNA — never use it for a
// 256-thread block reduction (R5's bug).
// ---------------------------------------------------------------------------
__global__ __launch_bounds__(TPB) void gru_kernel(
    const int*   __restrict__ ids,  const float* __restrict__ msg,
    const float* __restrict__ ts,   const float* __restrict__ mem,
    const float* __restrict__ b_ih, const float* __restrict__ b_hh,
    const float4* __restrict__ wt,
    float* __restrict__ out_mem,    float* __restrict__ out_lu,
    int B) {

    __shared__ float4 sxh[2][RPB][D4];   // [0]=x (messages), [1]=h (gathered memory)
    __shared__ int    s_id[RPB];
    __shared__ int    s_dup[RPB];

    const int tid  = threadIdx.x;
    const int base = blockIdx.x * RPB;

    if (tid < RPB) {
        s_id[tid]  = ids[base + tid];
        s_dup[tid] = 0;
    }
    __syncthreads();

    for (int it = tid; it < 2 * RPB * D4; it += TPB) {
        int which = it / (RPB * D4);
        int rem   = it - which * (RPB * D4);
        int r     = rem / D4;
        int k4    = rem - r * D4;
        const float* src = which ? (mem + (long)s_id[r] * D)
                                 : (msg + (long)(base + r) * D);
        ((float4*)sxh)[it] = *(const float4*)(src + 4 * k4);
    }
    // duplicate scan: row r loses if any later batch index has the same id
    for (int r = 0; r < RPB; ++r) {
        int my = s_id[r];
        for (int j = base + r + 1 + tid; j < B; j += TPB) {
            if (ids[j] == my) { s_dup[r] = 1; break; }
        }
    }
    __syncthreads();

    if (tid < D) {
        float acc[6][RPB];
        #pragma unroll
        for (int g = 0; g < 6; ++g)
            #pragma unroll
            for (int r = 0; r < RPB; ++r) acc[g][r] = 0.0f;

        const float4* wtB = wt + WT_HALF;
        for (int k4 = 0; k4 < D4; ++k4) {
            const int o = k4 * G3 + tid;
            float4 a0 = wt [o];
            float4 a1 = wt [o + D];
            float4 a2 = wt [o + 2 * D];
            float4 c0 = wtB[o];
            float4 c1 = wtB[o + D];
            float4 c2 = wtB[o + 2 * D];
            #pragma unroll
            for (int r = 0; r < RPB; ++r) {
                float4 xv = sxh[0][r][k4];
                float4 hv = sxh[1][r][k4];
                acc[0][r] += a0.x * xv.x + a0.y * xv.y + a0.z * xv.z + a0.w * xv.w;
                acc[1][r] += a1.x * xv.x + a1.y * xv.y + a1.z * xv.z + a1.w * xv.w;
                acc[2][r] += a2.x * xv.x + a2.y * xv.y + a2.z * xv.z + a2.w * xv.w;
                acc[3][r] += c0.x * hv.x + c0.y * hv.y + c0.z * hv.z + c0.w * hv.w;
                acc[4][r] += c1.x * hv.x + c1.y * hv.y + c1.z * hv.z + c1.w * hv.w;
                acc[5][r] += c2.x * hv.x + c2.y * hv.y + c2.z * hv.z + c2.w * hv.w;
            }
        }

        float bir = b_ih[tid], biz = b_ih[D + tid], bin_ = b_ih[2 * D + tid];
        float bhr = b_hh[tid], bhz = b_hh[D + tid], bhn  = b_hh[2 * D + tid];
        #pragma unroll
        for (int r = 0; r < RPB; ++r) {
            float i_r = acc[0][r] + bir;
            float i_z = acc[1][r] + biz;
            float i_n = acc[2][r] + bin_;
            float h_r = acc[3][r] + bhr;
            float h_z = acc[4][r] + bhz;
            float h_n = acc[5][r] + bhn;
            float rg = 1.0f / (1.0f + expf(-(i_r + h_r)));
            float zg = 1.0f / (1.0f + expf(-(i_z + h_z)));
            float ng = tanhf(i_n + rg * h_n);
            float hv = ((const float*)sxh[1][r])[tid];
            float outv = (1.0f - zg) * ng + zg * hv;
            if (!s_dup[r]) out_mem[(long)s_id[r] * D + tid] = outv;
        }
    }
    if (tid < RPB && !s_dup[tid]) out_lu[s_id[tid]] = ts[base + tid];
}

// ---------------- fallback GRU (uncoalesced weights, if ws too small) ------
__global__ __launch_bounds__(TPB) void gru_direct_kernel(
    const int*   __restrict__ ids,  const float* __restrict__ msg,
    const float* __restrict__ ts,   const float* __restrict__ mem,
    const float* __restrict__ w_ih, const float* __restrict__ w_hh,
    const float* __restrict__ b_ih, const float* __restrict__ b_hh,
    float* __restrict__ out_mem,    float* __restrict__ out_lu, int B) {
    int r = blockIdx.x;
    int tid = threadIdx.x;
    __shared__ float sx[D], sh[D];
    __shared__ int s_id, s_dup;
    if (tid == 0) { s_id = ids[r]; s_dup = 0; }
    __syncthreads();
    if (tid < D) { sx[tid] = msg[(long)r * D + tid]; sh[tid] = mem[(long)s_id * D + tid]; }
    for (int j = r + 1 + tid; j < B; j += TPB) if (ids[j] == s_id) { s_dup = 1; break; }
    __syncthreads();
    if (s_dup) return;
    if (tid < D) {
        float a[6] = {0,0,0,0,0,0};
        for (int k = 0; k < D; ++k) {
            float xv = sx[k], hv = sh[k];
            a[0] += w_ih[(long)(0*D+tid)*D+k] * xv;
            a[1] += w_ih[(long)(1*D+tid)*D+k] * xv;
            a[2] += w_ih[(long)(2*D+tid)*D+k] * xv;
            a[3] += w_hh[(long)(0*D+tid)*D+k] * hv;
            a[4] += w_hh[(long)(1*D+tid)*D+k] * hv;
            a[5] += w_hh[(long)(2*D+tid)*D+k] * hv;
        }
        float rg = 1.0f / (1.0f + expf(-(a[0] + b_ih[tid] + a[3] + b_hh[tid])));
        float zg = 1.0f / (1.0f + expf(-(a[1] + b_ih[D+tid] + a[4] + b_hh[D+tid])));
        float ng = tanhf(a[2] + b_ih[2*D+tid] + rg * (a[5] + b_hh[2*D+tid]));
        out_mem[(long)s_id * D + tid] = (1.0f - zg) * ng + zg * sh[tid];
    }
    if (tid == 0) out_lu[s_id] = ts[r];
}

extern "C" void kernel_launch(void* const* d_in, const int* in_sizes, int n_in,
                              void* d_out, int out_size, void* d_ws, size_t ws_size,
                              hipStream_t stream) {
    const int*   node_ids    = (const int*)d_in[0];
    const float* messages    = (const float*)d_in[1];
    const float* timestamps  = (const float*)d_in[2];
    const float* memory      = (const float*)d_in[3];
    const float* last_update = (const float*)d_in[4];
    const float* w_ih        = (const float*)d_in[5];
    const float* w_hh        = (const float*)d_in[6];
    const float* b_ih        = (const float*)d_in[7];
    const float* b_hh        = (const float*)d_in[8];
    float* out = (float*)d_out;

    const int B = in_sizes[0];          // 4096
    const int N = in_sizes[4];          // 500000
    const long memf = (long)N * D;      // 86,000,000 floats

    const unsigned quads_mem   = (unsigned)(memf / 16);         // 5,375,000
    const unsigned quads_total = quads_mem + (unsigned)(N / 16); // +31,250
    const unsigned nblk        = (quads_total + TPB - 1) / TPB;  // 21,119

    copy4_kernel<<<nblk, TPB, 0, stream>>>((const vfloat4*)memory,
                                           (vfloat4*)out,
                                           (const vfloat4*)last_update,
                                           (vfloat4*)(out + memf),
                                           quads_mem, quads_total);

    const size_t wt_bytes = (size_t)WT_F4 * sizeof(float4);
    if (ws_size >= wt_bytes) {
        float4* wt = (float4*)d_ws;
        prep_kernel<<<(WT_F4 + 255) / 256, 256, 0, stream>>>(w_ih, w_hh, wt);
        gru_kernel<<<B / RPB, TPB, 0, stream>>>(node_ids, messages, timestamps, memory,
                                                b_ih, b_hh, (const float4*)wt,
                                                out, out + memf, B);
    } else {
        gru_direct_kernel<<<B, TPB, 0, stream>>>(node_ids, messages, timestamps, memory,
                                                 w_ih, w_hh, b_ih, b_hh,
                                                 out, out + memf, B);
    }
}

// Round 13
// 188.780 us; speedup vs baseline: 1.2209x; 1.1344x over previous
//
#include <hip/hip_runtime.h>
#include <math.h>

#define D     172
#define D4    43            // float4s per row
#define G3    516           // 3*D rows per weight matrix
#define RPB   8             // batch rows per GRU block
#define TPB   256
#define WT_HALF (43 * 516)          // float4s per transposed matrix = 22188
#define WT_F4   (2 * WT_HALF)       // 44376

typedef float vfloat4 __attribute__((ext_vector_type(4)));

// ---------------------------------------------------------------------------
// Prologue: transpose weights into ws as Wt[m][k4][row] (float4 over k) so
// GRU weight loads are coalesced across lanes (lane d -> consecutive f4).
// ---------------------------------------------------------------------------
__global__ __launch_bounds__(256) void prep_kernel(const float* __restrict__ w_ih,
                                                   const float* __restrict__ w_hh,
                                                   float4* __restrict__ wt) {
    int idx = blockIdx.x * 256 + threadIdx.x;
    if (idx < WT_F4) {
        int m   = idx / WT_HALF;
        int rem = idx - m * WT_HALF;
        int k4  = rem / G3;
        int row = rem - k4 * G3;
        const float* src = m ? w_hh : w_ih;
        wt[idx] = *(const float4*)(src + (long)row * D + 4 * k4);
    }
}

// ---------------------------------------------------------------------------
// Copy kernel — monolithic (no loop: R10's win), TWO float4s per thread at a
// HALF-BUFFER offset so BOTH accesses keep full intra-wave coalescing
// (consecutive lanes -> consecutive 16B; 16 cachelines/instr). R12's mistake
// was adjacent-quad batching (stride-64B per lane = 64 lines/instr, ~4x
// coalescer cost, +30us). Loads issued before stores -> 32B/lane in flight.
// memf4 = 21,500,000 = 2*10,750,000; luf4 = 125,000 = 2*62,500.
// ---------------------------------------------------------------------------
__global__ __launch_bounds__(TPB) void copy2_kernel(const vfloat4* __restrict__ src,
                                                    vfloat4* __restrict__ dst,
                                                    const vfloat4* __restrict__ lu4,
                                                    vfloat4* __restrict__ outlu4,
                                                    unsigned hmem, unsigned hlu) {
    unsigned gid = blockIdx.x * TPB + threadIdx.x;
    if (gid < hmem) {
        vfloat4 a = src[gid];
        vfloat4 b = src[gid + hmem];
        dst[gid]        = a;
        dst[gid + hmem] = b;
    } else if (gid < hmem + hlu) {
        unsigned e = gid - hmem;
        vfloat4 a = lu4[e];
        vfloat4 b = lu4[e + hlu];
        outlu4[e]       = a;
        outlu4[e + hlu] = b;
    }
}

// ---------------------------------------------------------------------------
// GRU kernel (runs AFTER the bulk copy): computes 8 batch rows per block and
// scatters winner rows + timestamps directly into the output. Dup
// suppression: shared-memory flag any thread may set (benign OR-race);
// NOTE: __ballot is per-wave (64 lanes) on CDNA — never use it for a
// 256-thread block reduction (R5's bug).
// ---------------------------------------------------------------------------
__global__ __launch_bounds__(TPB) void gru_kernel(
    const int*   __restrict__ ids,  const float* __restrict__ msg,
    const float* __restrict__ ts,   const float* __restrict__ mem,
    const float* __restrict__ b_ih, const float* __restrict__ b_hh,
    const float4* __restrict__ wt,
    float* __restrict__ out_mem,    float* __restrict__ out_lu,
    int B) {

    __shared__ float4 sxh[2][RPB][D4];   // [0]=x (messages), [1]=h (gathered memory)
    __shared__ int    s_id[RPB];
    __shared__ int    s_dup[RPB];

    const int tid  = threadIdx.x;
    const int base = blockIdx.x * RPB;

    if (tid < RPB) {
        s_id[tid]  = ids[base + tid];
        s_dup[tid] = 0;
    }
    __syncthreads();

    for (int it = tid; it < 2 * RPB * D4; it += TPB) {
        int which = it / (RPB * D4);
        int rem   = it - which * (RPB * D4);
        int r     = rem / D4;
        int k4    = rem - r * D4;
        const float* src = which ? (mem + (long)s_id[r] * D)
                                 : (msg + (long)(base + r) * D);
        ((float4*)sxh)[it] = *(const float4*)(src + 4 * k4);
    }
    // duplicate scan: row r loses if any later batch index has the same id
    for (int r = 0; r < RPB; ++r) {
        int my = s_id[r];
        for (int j = base + r + 1 + tid; j < B; j += TPB) {
            if (ids[j] == my) { s_dup[r] = 1; break; }
        }
    }
    __syncthreads();

    if (tid < D) {
        float acc[6][RPB];
        #pragma unroll
        for (int g = 0; g < 6; ++g)
            #pragma unroll
            for (int r = 0; r < RPB; ++r) acc[g][r] = 0.0f;

        const float4* wtB = wt + WT_HALF;
        for (int k4 = 0; k4 < D4; ++k4) {
            const int o = k4 * G3 + tid;
            float4 a0 = wt [o];
            float4 a1 = wt [o + D];
            float4 a2 = wt [o + 2 * D];
            float4 c0 = wtB[o];
            float4 c1 = wtB[o + D];
            float4 c2 = wtB[o + 2 * D];
            #pragma unroll
            for (int r = 0; r < RPB; ++r) {
                float4 xv = sxh[0][r][k4];
                float4 hv = sxh[1][r][k4];
                acc[0][r] += a0.x * xv.x + a0.y * xv.y + a0.z * xv.z + a0.w * xv.w;
                acc[1][r] += a1.x * xv.x + a1.y * xv.y + a1.z * xv.z + a1.w * xv.w;
                acc[2][r] += a2.x * xv.x + a2.y * xv.y + a2.z * xv.z + a2.w * xv.w;
                acc[3][r] += c0.x * hv.x + c0.y * hv.y + c0.z * hv.z + c0.w * hv.w;
                acc[4][r] += c1.x * hv.x + c1.y * hv.y + c1.z * hv.z + c1.w * hv.w;
                acc[5][r] += c2.x * hv.x + c2.y * hv.y + c2.z * hv.z + c2.w * hv.w;
            }
        }

        float bir = b_ih[tid], biz = b_ih[D + tid], bin_ = b_ih[2 * D + tid];
        float bhr = b_hh[tid], bhz = b_hh[D + tid], bhn  = b_hh[2 * D + tid];
        #pragma unroll
        for (int r = 0; r < RPB; ++r) {
            float i_r = acc[0][r] + bir;
            float i_z = acc[1][r] + biz;
            float i_n = acc[2][r] + bin_;
            float h_r = acc[3][r] + bhr;
            float h_z = acc[4][r] + bhz;
            float h_n = acc[5][r] + bhn;
            float rg = 1.0f / (1.0f + expf(-(i_r + h_r)));
            float zg = 1.0f / (1.0f + expf(-(i_z + h_z)));
            float ng = tanhf(i_n + rg * h_n);
            float hv = ((const float*)sxh[1][r])[tid];
            float outv = (1.0f - zg) * ng + zg * hv;
            if (!s_dup[r]) out_mem[(long)s_id[r] * D + tid] = outv;
        }
    }
    if (tid < RPB && !s_dup[tid]) out_lu[s_id[tid]] = ts[base + tid];
}

// ---------------- fallback GRU (uncoalesced weights, if ws too small) ------
__global__ __launch_bounds__(TPB) void gru_direct_kernel(
    const int*   __restrict__ ids,  const float* __restrict__ msg,
    const float* __restrict__ ts,   const float* __restrict__ mem,
    const float* __restrict__ w_ih, const float* __restrict__ w_hh,
    const float* __restrict__ b_ih, const float* __restrict__ b_hh,
    float* __restrict__ out_mem,    float* __restrict__ out_lu, int B) {
    int r = blockIdx.x;
    int tid = threadIdx.x;
    __shared__ float sx[D], sh[D];
    __shared__ int s_id, s_dup;
    if (tid == 0) { s_id = ids[r]; s_dup = 0; }
    __syncthreads();
    if (tid < D) { sx[tid] = msg[(long)r * D + tid]; sh[tid] = mem[(long)s_id * D + tid]; }
    for (int j = r + 1 + tid; j < B; j += TPB) if (ids[j] == s_id) { s_dup = 1; break; }
    __syncthreads();
    if (s_dup) return;
    if (tid < D) {
        float a[6] = {0,0,0,0,0,0};
        for (int k = 0; k < D; ++k) {
            float xv = sx[k], hv = sh[k];
            a[0] += w_ih[(long)(0*D+tid)*D+k] * xv;
            a[1] += w_ih[(long)(1*D+tid)*D+k] * xv;
            a[2] += w_ih[(long)(2*D+tid)*D+k] * xv;
            a[3] += w_hh[(long)(0*D+tid)*D+k] * hv;
            a[4] += w_hh[(long)(1*D+tid)*D+k] * hv;
            a[5] += w_hh[(long)(2*D+tid)*D+k] * hv;
        }
        float rg = 1.0f / (1.0f + expf(-(a[0] + b_ih[tid] + a[3] + b_hh[tid])));
        float zg = 1.0f / (1.0f + expf(-(a[1] + b_ih[D+tid] + a[4] + b_hh[D+tid])));
        float ng = tanhf(a[2] + b_ih[2*D+tid] + rg * (a[5] + b_hh[2*D+tid]));
        out_mem[(long)s_id * D + tid] = (1.0f - zg) * ng + zg * sh[tid];
    }
    if (tid == 0) out_lu[s_id] = ts[r];
}

extern "C" void kernel_launch(void* const* d_in, const int* in_sizes, int n_in,
                              void* d_out, int out_size, void* d_ws, size_t ws_size,
                              hipStream_t stream) {
    const int*   node_ids    = (const int*)d_in[0];
    const float* messages    = (const float*)d_in[1];
    const float* timestamps  = (const float*)d_in[2];
    const float* memory      = (const float*)d_in[3];
    const float* last_update = (const float*)d_in[4];
    const float* w_ih        = (const float*)d_in[5];
    const float* w_hh        = (const float*)d_in[6];
    const float* b_ih        = (const float*)d_in[7];
    const float* b_hh        = (const float*)d_in[8];
    float* out = (float*)d_out;

    const int B = in_sizes[0];          // 4096
    const int N = in_sizes[4];          // 500000
    const long memf = (long)N * D;      // 86,000,000 floats

    const unsigned hmem = (unsigned)(memf / 8);   // 10,750,000 f4 pairs
    const unsigned hlu  = (unsigned)(N / 8);      // 62,500
    const unsigned nthreads = hmem + hlu;         // 10,812,500
    const unsigned nblk = (nthreads + TPB - 1) / TPB;  // 42,237

    copy2_kernel<<<nblk, TPB, 0, stream>>>((const vfloat4*)memory,
                                           (vfloat4*)out,
                                           (const vfloat4*)last_update,
                                           (vfloat4*)(out + memf),
                                           hmem, hlu);

    const size_t wt_bytes = (size_t)WT_F4 * sizeof(float4);
    if (ws_size >= wt_bytes) {
        float4* wt = (float4*)d_ws;
        prep_kernel<<<(WT_F4 + 255) / 256, 256, 0, stream>>>(w_ih, w_hh, wt);
        gru_kernel<<<B / RPB, TPB, 0, stream>>>(node_ids, messages, timestamps, memory,
                                                b_ih, b_hh, (const float4*)wt,
                                                out, out + memf, B);
    } else {
        gru_direct_kernel<<<B, TPB, 0, stream>>>(node_ids, messages, timestamps, memory,
                                                 w_ih, w_hh, b_ih, b_hh,
                                                 out, out + memf, B);
    }
}

// Round 14
// 186.747 us; speedup vs baseline: 1.2342x; 1.0109x over previous
//
#include <hip/hip_runtime.h>
#include <math.h>

#define D     172
#define D4    43            // float4s per row
#define G3    516           // 3*D rows per weight matrix
#define RPB   8             // batch rows per GRU block
#define TPB   256
#define CTPB  1024          // copy block size (16 waves/block)
#define WT_HALF (43 * 516)          // float4s per transposed matrix = 22188
#define WT_F4   (2 * WT_HALF)       // 44376

typedef float vfloat4 __attribute__((ext_vector_type(4)));

// ---------------------------------------------------------------------------
// Prologue: transpose weights into ws as Wt[m][k4][row] (float4 over k) so
// GRU weight loads are coalesced across lanes (lane d -> consecutive f4).
// ---------------------------------------------------------------------------
__global__ __launch_bounds__(256) void prep_kernel(const float* __restrict__ w_ih,
                                                   const float* __restrict__ w_hh,
                                                   float4* __restrict__ wt) {
    int idx = blockIdx.x * 256 + threadIdx.x;
    if (idx < WT_F4) {
        int m   = idx / WT_HALF;
        int rem = idx - m * WT_HALF;
        int k4  = rem / G3;
        int row = rem - k4 * G3;
        const float* src = m ? w_hh : w_ih;
        wt[idx] = *(const float4*)(src + (long)row * D + 4 * k4);
    }
}

// ---------------------------------------------------------------------------
// Copy kernel — monolithic one-float4-per-thread (R10's proven-best form:
// no loop, perfect coalescing), but 1024-thread blocks. R10 ran at 60%
// occupancy with 20 VGPR / no LDS -> block-slot/dispatch churn limited
// (84k 4-wave blocks). 16-wave blocks cut the block count 4x at identical
// per-thread work. Copy ledger: one-shot 150us < MLP2-half 157 < quad-adj
// (broken coalescing) < loops 215+ < fused-fat 230.
// ---------------------------------------------------------------------------
__global__ __launch_bounds__(CTPB) void copy1_kernel(const vfloat4* __restrict__ src,
                                                     vfloat4* __restrict__ dst,
                                                     const vfloat4* __restrict__ lu4,
                                                     vfloat4* __restrict__ outlu4,
                                                     unsigned memf4, unsigned totalf4) {
    unsigned gid = blockIdx.x * CTPB + threadIdx.x;
    if (gid < memf4) {
        dst[gid] = src[gid];
    } else if (gid < totalf4) {
        outlu4[gid - memf4] = lu4[gid - memf4];
    }
}

// ---------------------------------------------------------------------------
// GRU kernel (runs AFTER the bulk copy): computes 8 batch rows per block and
// scatters winner rows + timestamps directly into the output. Dup
// suppression: shared-memory flag any thread may set (benign OR-race);
// NOTE: __ballot is per-wave (64 lanes) on CDNA — never use it for a
// 256-thread block reduction (R5's bug).
// ---------------------------------------------------------------------------
__global__ __launch_bounds__(TPB) void gru_kernel(
    const int*   __restrict__ ids,  const float* __restrict__ msg,
    const float* __restrict__ ts,   const float* __restrict__ mem,
    const float* __restrict__ b_ih, const float* __restrict__ b_hh,
    const float4* __restrict__ wt,
    float* __restrict__ out_mem,    float* __restrict__ out_lu,
    int B) {

    __shared__ float4 sxh[2][RPB][D4];   // [0]=x (messages), [1]=h (gathered memory)
    __shared__ int    s_id[RPB];
    __shared__ int    s_dup[RPB];

    const int tid  = threadIdx.x;
    const int base = blockIdx.x * RPB;

    if (tid < RPB) {
        s_id[tid]  = ids[base + tid];
        s_dup[tid] = 0;
    }
    __syncthreads();

    for (int it = tid; it < 2 * RPB * D4; it += TPB) {
        int which = it / (RPB * D4);
        int rem   = it - which * (RPB * D4);
        int r     = rem / D4;
        int k4    = rem - r * D4;
        const float* src = which ? (mem + (long)s_id[r] * D)
                                 : (msg + (long)(base + r) * D);
        ((float4*)sxh)[it] = *(const float4*)(src + 4 * k4);
    }
    // duplicate scan: row r loses if any later batch index has the same id
    for (int r = 0; r < RPB; ++r) {
        int my = s_id[r];
        for (int j = base + r + 1 + tid; j < B; j += TPB) {
            if (ids[j] == my) { s_dup[r] = 1; break; }
        }
    }
    __syncthreads();

    if (tid < D) {
        float acc[6][RPB];
        #pragma unroll
        for (int g = 0; g < 6; ++g)
            #pragma unroll
            for (int r = 0; r < RPB; ++r) acc[g][r] = 0.0f;

        const float4* wtB = wt + WT_HALF;
        for (int k4 = 0; k4 < D4; ++k4) {
            const int o = k4 * G3 + tid;
            float4 a0 = wt [o];
            float4 a1 = wt [o + D];
            float4 a2 = wt [o + 2 * D];
            float4 c0 = wtB[o];
            float4 c1 = wtB[o + D];
            float4 c2 = wtB[o + 2 * D];
            #pragma unroll
            for (int r = 0; r < RPB; ++r) {
                float4 xv = sxh[0][r][k4];
                float4 hv = sxh[1][r][k4];
                acc[0][r] += a0.x * xv.x + a0.y * xv.y + a0.z * xv.z + a0.w * xv.w;
                acc[1][r] += a1.x * xv.x + a1.y * xv.y + a1.z * xv.z + a1.w * xv.w;
                acc[2][r] += a2.x * xv.x + a2.y * xv.y + a2.z * xv.z + a2.w * xv.w;
                acc[3][r] += c0.x * hv.x + c0.y * hv.y + c0.z * hv.z + c0.w * hv.w;
                acc[4][r] += c1.x * hv.x + c1.y * hv.y + c1.z * hv.z + c1.w * hv.w;
                acc[5][r] += c2.x * hv.x + c2.y * hv.y + c2.z * hv.z + c2.w * hv.w;
            }
        }

        float bir = b_ih[tid], biz = b_ih[D + tid], bin_ = b_ih[2 * D + tid];
        float bhr = b_hh[tid], bhz = b_hh[D + tid], bhn  = b_hh[2 * D + tid];
        #pragma unroll
        for (int r = 0; r < RPB; ++r) {
            float i_r = acc[0][r] + bir;
            float i_z = acc[1][r] + biz;
            float i_n = acc[2][r] + bin_;
            float h_r = acc[3][r] + bhr;
            float h_z = acc[4][r] + bhz;
            float h_n = acc[5][r] + bhn;
            float rg = 1.0f / (1.0f + expf(-(i_r + h_r)));
            float zg = 1.0f / (1.0f + expf(-(i_z + h_z)));
            float ng = tanhf(i_n + rg * h_n);
            float hv = ((const float*)sxh[1][r])[tid];
            float outv = (1.0f - zg) * ng + zg * hv;
            if (!s_dup[r]) out_mem[(long)s_id[r] * D + tid] = outv;
        }
    }
    if (tid < RPB && !s_dup[tid]) out_lu[s_id[tid]] = ts[base + tid];
}

// ---------------- fallback GRU (uncoalesced weights, if ws too small) ------
__global__ __launch_bounds__(TPB) void gru_direct_kernel(
    const int*   __restrict__ ids,  const float* __restrict__ msg,
    const float* __restrict__ ts,   const float* __restrict__ mem,
    const float* __restrict__ w_ih, const float* __restrict__ w_hh,
    const float* __restrict__ b_ih, const float* __restrict__ b_hh,
    float* __restrict__ out_mem,    float* __restrict__ out_lu, int B) {
    int r = blockIdx.x;
    int tid = threadIdx.x;
    __shared__ float sx[D], sh[D];
    __shared__ int s_id, s_dup;
    if (tid == 0) { s_id = ids[r]; s_dup = 0; }
    __syncthreads();
    if (tid < D) { sx[tid] = msg[(long)r * D + tid]; sh[tid] = mem[(long)s_id * D + tid]; }
    for (int j = r + 1 + tid; j < B; j += TPB) if (ids[j] == s_id) { s_dup = 1; break; }
    __syncthreads();
    if (s_dup) return;
    if (tid < D) {
        float a[6] = {0,0,0,0,0,0};
        for (int k = 0; k < D; ++k) {
            float xv = sx[k], hv = sh[k];
            a[0] += w_ih[(long)(0*D+tid)*D+k] * xv;
            a[1] += w_ih[(long)(1*D+tid)*D+k] * xv;
            a[2] += w_ih[(long)(2*D+tid)*D+k] * xv;
            a[3] += w_hh[(long)(0*D+tid)*D+k] * hv;
            a[4] += w_hh[(long)(1*D+tid)*D+k] * hv;
            a[5] += w_hh[(long)(2*D+tid)*D+k] * hv;
        }
        float rg = 1.0f / (1.0f + expf(-(a[0] + b_ih[tid] + a[3] + b_hh[tid])));
        float zg = 1.0f / (1.0f + expf(-(a[1] + b_ih[D+tid] + a[4] + b_hh[D+tid])));
        float ng = tanhf(a[2] + b_ih[2*D+tid] + rg * (a[5] + b_hh[2*D+tid]));
        out_mem[(long)s_id * D + tid] = (1.0f - zg) * ng + zg * sh[tid];
    }
    if (tid == 0) out_lu[s_id] = ts[r];
}

extern "C" void kernel_launch(void* const* d_in, const int* in_sizes, int n_in,
                              void* d_out, int out_size, void* d_ws, size_t ws_size,
                              hipStream_t stream) {
    const int*   node_ids    = (const int*)d_in[0];
    const float* messages    = (const float*)d_in[1];
    const float* timestamps  = (const float*)d_in[2];
    const float* memory      = (const float*)d_in[3];
    const float* last_update = (const float*)d_in[4];
    const float* w_ih        = (const float*)d_in[5];
    const float* w_hh        = (const float*)d_in[6];
    const float* b_ih        = (const float*)d_in[7];
    const float* b_hh        = (const float*)d_in[8];
    float* out = (float*)d_out;

    const int B = in_sizes[0];          // 4096
    const int N = in_sizes[4];          // 500000
    const long memf = (long)N * D;      // 86,000,000 floats

    const unsigned memf4   = (unsigned)(memf / 4);       // 21,500,000
    const unsigned totalf4 = memf4 + (unsigned)(N / 4);  // +125,000
    const unsigned nblk    = (totalf4 + CTPB - 1) / CTPB; // 21,119

    copy1_kernel<<<nblk, CTPB, 0, stream>>>((const vfloat4*)memory,
                                            (vfloat4*)out,
                                            (const vfloat4*)last_update,
                                            (vfloat4*)(out + memf),
                                            memf4, totalf4);

    const size_t wt_bytes = (size_t)WT_F4 * sizeof(float4);
    if (ws_size >= wt_bytes) {
        float4* wt = (float4*)d_ws;
        prep_kernel<<<(WT_F4 + 255) / 256, 256, 0, stream>>>(w_ih, w_hh, wt);
        gru_kernel<<<B / RPB, TPB, 0, stream>>>(node_ids, messages, timestamps, memory,
                                                b_ih, b_hh, (const float4*)wt,
                                                out, out + memf, B);
    } else {
        gru_direct_kernel<<<B, TPB, 0, stream>>>(node_ids, messages, timestamps, memory,
                                                 w_ih, w_hh, b_ih, b_hh,
                                                 out, out + memf, B);
    }
}

// Round 15
// 181.522 us; speedup vs baseline: 1.2697x; 1.0288x over previous
//
#include <hip/hip_runtime.h>
#include <math.h>

#define D     172
#define D4    43            // float4s per row
#define G3    516           // 3*D rows per weight matrix
#define RPB   8             // batch rows per GRU block
#define TPB   256
#define WT_HALF (43 * 516)          // float4s per transposed matrix = 22188
#define WT_F4   (2 * WT_HALF)       // 44376

typedef float vfloat4 __attribute__((ext_vector_type(4)));

// ---------------------------------------------------------------------------
// Prologue: transpose weights into ws as Wt[m][k4][row] (float4 over k) so
// GRU weight loads are coalesced across lanes (lane d -> consecutive f4).
// ---------------------------------------------------------------------------
__global__ __launch_bounds__(256) void prep_kernel(const float* __restrict__ w_ih,
                                                   const float* __restrict__ w_hh,
                                                   float4* __restrict__ wt) {
    int idx = blockIdx.x * 256 + threadIdx.x;
    if (idx < WT_F4) {
        int m   = idx / WT_HALF;
        int rem = idx - m * WT_HALF;
        int k4  = rem / G3;
        int row = rem - k4 * G3;
        const float* src = m ? w_hh : w_ih;
        wt[idx] = *(const float4*)(src + (long)row * D + 4 * k4);
    }
}

// ---------------------------------------------------------------------------
// Copy kernel — R10's proven-best form, restored exactly: monolithic
// one-float4-per-thread, 256-thread blocks, no loop, perfect coalescing.
// Ledger (total us): this=181.8 < 1024-blk=186.7 < MLP2=188.8 < blit=200.3
// < NT-loop=215 < quad-adj=214 < loops=222+ < fat-fused=230. Matches/beats
// the vendor blit; mixed read+write stream on a >L3 working set is the
// structural limit (~4.4 TB/s nominal; write-only fill does 6.9).
// ---------------------------------------------------------------------------
__global__ __launch_bounds__(TPB) void copy1_kernel(const vfloat4* __restrict__ src,
                                                    vfloat4* __restrict__ dst,
                                                    const vfloat4* __restrict__ lu4,
                                                    vfloat4* __restrict__ outlu4,
                                                    unsigned memf4, unsigned totalf4) {
    unsigned gid = blockIdx.x * TPB + threadIdx.x;
    if (gid < memf4) {
        dst[gid] = src[gid];
    } else if (gid < totalf4) {
        outlu4[gid - memf4] = lu4[gid - memf4];
    }
}

// ---------------------------------------------------------------------------
// GRU kernel (runs AFTER the bulk copy): computes 8 batch rows per block and
// scatters winner rows + timestamps directly into the output. Dup
// suppression: shared-memory flag any thread may set (benign OR-race);
// NOTE: __ballot is per-wave (64 lanes) on CDNA — never use it for a
// 256-thread block reduction (R5's bug).
// ---------------------------------------------------------------------------
__global__ __launch_bounds__(TPB) void gru_kernel(
    const int*   __restrict__ ids,  const float* __restrict__ msg,
    const float* __restrict__ ts,   const float* __restrict__ mem,
    const float* __restrict__ b_ih, const float* __restrict__ b_hh,
    const float4* __restrict__ wt,
    float* __restrict__ out_mem,    float* __restrict__ out_lu,
    int B) {

    __shared__ float4 sxh[2][RPB][D4];   // [0]=x (messages), [1]=h (gathered memory)
    __shared__ int    s_id[RPB];
    __shared__ int    s_dup[RPB];

    const int tid  = threadIdx.x;
    const int base = blockIdx.x * RPB;

    if (tid < RPB) {
        s_id[tid]  = ids[base + tid];
        s_dup[tid] = 0;
    }
    __syncthreads();

    for (int it = tid; it < 2 * RPB * D4; it += TPB) {
        int which = it / (RPB * D4);
        int rem   = it - which * (RPB * D4);
        int r     = rem / D4;
        int k4    = rem - r * D4;
        const float* src = which ? (mem + (long)s_id[r] * D)
                                 : (msg + (long)(base + r) * D);
        ((float4*)sxh)[it] = *(const float4*)(src + 4 * k4);
    }
    // duplicate scan: row r loses if any later batch index has the same id
    for (int r = 0; r < RPB; ++r) {
        int my = s_id[r];
        for (int j = base + r + 1 + tid; j < B; j += TPB) {
            if (ids[j] == my) { s_dup[r] = 1; break; }
        }
    }
    __syncthreads();

    if (tid < D) {
        float acc[6][RPB];
        #pragma unroll
        for (int g = 0; g < 6; ++g)
            #pragma unroll
            for (int r = 0; r < RPB; ++r) acc[g][r] = 0.0f;

        const float4* wtB = wt + WT_HALF;
        for (int k4 = 0; k4 < D4; ++k4) {
            const int o = k4 * G3 + tid;
            float4 a0 = wt [o];
            float4 a1 = wt [o + D];
            float4 a2 = wt [o + 2 * D];
            float4 c0 = wtB[o];
            float4 c1 = wtB[o + D];
            float4 c2 = wtB[o + 2 * D];
            #pragma unroll
            for (int r = 0; r < RPB; ++r) {
                float4 xv = sxh[0][r][k4];
                float4 hv = sxh[1][r][k4];
                acc[0][r] += a0.x * xv.x + a0.y * xv.y + a0.z * xv.z + a0.w * xv.w;
                acc[1][r] += a1.x * xv.x + a1.y * xv.y + a1.z * xv.z + a1.w * xv.w;
                acc[2][r] += a2.x * xv.x + a2.y * xv.y + a2.z * xv.z + a2.w * xv.w;
                acc[3][r] += c0.x * hv.x + c0.y * hv.y + c0.z * hv.z + c0.w * hv.w;
                acc[4][r] += c1.x * hv.x + c1.y * hv.y + c1.z * hv.z + c1.w * hv.w;
                acc[5][r] += c2.x * hv.x + c2.y * hv.y + c2.z * hv.z + c2.w * hv.w;
            }
        }

        float bir = b_ih[tid], biz = b_ih[D + tid], bin_ = b_ih[2 * D + tid];
        float bhr = b_hh[tid], bhz = b_hh[D + tid], bhn  = b_hh[2 * D + tid];
        #pragma unroll
        for (int r = 0; r < RPB; ++r) {
            float i_r = acc[0][r] + bir;
            float i_z = acc[1][r] + biz;
            float i_n = acc[2][r] + bin_;
            float h_r = acc[3][r] + bhr;
            float h_z = acc[4][r] + bhz;
            float h_n = acc[5][r] + bhn;
            float rg = 1.0f / (1.0f + expf(-(i_r + h_r)));
            float zg = 1.0f / (1.0f + expf(-(i_z + h_z)));
            float ng = tanhf(i_n + rg * h_n);
            float hv = ((const float*)sxh[1][r])[tid];
            float outv = (1.0f - zg) * ng + zg * hv;
            if (!s_dup[r]) out_mem[(long)s_id[r] * D + tid] = outv;
        }
    }
    if (tid < RPB && !s_dup[tid]) out_lu[s_id[tid]] = ts[base + tid];
}

// ---------------- fallback GRU (uncoalesced weights, if ws too small) ------
__global__ __launch_bounds__(TPB) void gru_direct_kernel(
    const int*   __restrict__ ids,  const float* __restrict__ msg,
    const float* __restrict__ ts,   const float* __restrict__ mem,
    const float* __restrict__ w_ih, const float* __restrict__ w_hh,
    const float* __restrict__ b_ih, const float* __restrict__ b_hh,
    float* __restrict__ out_mem,    float* __restrict__ out_lu, int B) {
    int r = blockIdx.x;
    int tid = threadIdx.x;
    __shared__ float sx[D], sh[D];
    __shared__ int s_id, s_dup;
    if (tid == 0) { s_id = ids[r]; s_dup = 0; }
    __syncthreads();
    if (tid < D) { sx[tid] = msg[(long)r * D + tid]; sh[tid] = mem[(long)s_id * D + tid]; }
    for (int j = r + 1 + tid; j < B; j += TPB) if (ids[j] == s_id) { s_dup = 1; break; }
    __syncthreads();
    if (s_dup) return;
    if (tid < D) {
        float a[6] = {0,0,0,0,0,0};
        for (int k = 0; k < D; ++k) {
            float xv = sx[k], hv = sh[k];
            a[0] += w_ih[(long)(0*D+tid)*D+k] * xv;
            a[1] += w_ih[(long)(1*D+tid)*D+k] * xv;
            a[2] += w_ih[(long)(2*D+tid)*D+k] * xv;
            a[3] += w_hh[(long)(0*D+tid)*D+k] * hv;
            a[4] += w_hh[(long)(1*D+tid)*D+k] * hv;
            a[5] += w_hh[(long)(2*D+tid)*D+k] * hv;
        }
        float rg = 1.0f / (1.0f + expf(-(a[0] + b_ih[tid] + a[3] + b_hh[tid])));
        float zg = 1.0f / (1.0f + expf(-(a[1] + b_ih[D+tid] + a[4] + b_hh[D+tid])));
        float ng = tanhf(a[2] + b_ih[2*D+tid] + rg * (a[5] + b_hh[2*D+tid]));
        out_mem[(long)s_id * D + tid] = (1.0f - zg) * ng + zg * sh[tid];
    }
    if (tid == 0) out_lu[s_id] = ts[r];
}

extern "C" void kernel_launch(void* const* d_in, const int* in_sizes, int n_in,
                              void* d_out, int out_size, void* d_ws, size_t ws_size,
                              hipStream_t stream) {
    const int*   node_ids    = (const int*)d_in[0];
    const float* messages    = (const float*)d_in[1];
    const float* timestamps  = (const float*)d_in[2];
    const float* memory      = (const float*)d_in[3];
    const float* last_update = (const float*)d_in[4];
    const float* w_ih        = (const float*)d_in[5];
    const float* w_hh        = (const float*)d_in[6];
    const float* b_ih        = (const float*)d_in[7];
    const float* b_hh        = (const float*)d_in[8];
    float* out = (float*)d_out;

    const int B = in_sizes[0];          // 4096
    const int N = in_sizes[4];          // 500000
    const long memf = (long)N * D;      // 86,000,000 floats

    const unsigned memf4   = (unsigned)(memf / 4);       // 21,500,000
    const unsigned totalf4 = memf4 + (unsigned)(N / 4);  // +125,000
    const unsigned nblk    = (totalf4 + TPB - 1) / TPB;  // 84,473

    copy1_kernel<<<nblk, TPB, 0, stream>>>((const vfloat4*)memory,
                                           (vfloat4*)out,
                                           (const vfloat4*)last_update,
                                           (vfloat4*)(out + memf),
                                           memf4, totalf4);

    const size_t wt_bytes = (size_t)WT_F4 * sizeof(float4);
    if (ws_size >= wt_bytes) {
        float4* wt = (float4*)d_ws;
        prep_kernel<<<(WT_F4 + 255) / 256, 256, 0, stream>>>(w_ih, w_hh, wt);
        gru_kernel<<<B / RPB, TPB, 0, stream>>>(node_ids, messages, timestamps, memory,
                                                b_ih, b_hh, (const float4*)wt,
                                                out, out + memf, B);
    } else {
        gru_direct_kernel<<<B, TPB, 0, stream>>>(node_ids, messages, timestamps, memory,
                                                 w_ih, w_hh, b_ih, b_hh,
                                                 out, out + memf, B);
    }
}